// Round 4
// baseline (31.050 us; speedup 1.0000x reference)
//
#include <hip/hip_runtime.h>

// Aspect-grouped 2-layer MLP, 2 dispatches.
//   fused_layer1: every block redundantly & deterministically buckets the 1024
//     aspect_ids (ballot histogram + stable ballot scan), maps blockIdx.x to
//     (aspect, 16-sample chunk), then: stage 16 X rows in LDS; 8 waves split
//     D=768 (96 rows each); thread owns 4 samples x 4 cols (16 FMA per W1
//     float4 load); LDS cross-wave reduce; bias+relu+W2 partial; 16-lane
//     shuffle; part[hs][orig_sample] = float2 partial logits.
//   finish: out[s][o] = b2[aid] + sum_hs part[hs][s][o].

constexpr int D  = 768;
constexpr int H  = 256;
constexpr int NA = 20;
constexpr int NB = 1024;
constexpr int S  = 16;            // samples per chunk
constexpr int CH_CAP = 96;        // >= max chunks = 64 + 20 = 84
constexpr int DP = D + 4;         // padded LDS row (3088 B, 16B-aligned)

constexpr size_t WS_NEEDED = (size_t)4 * NB * 2 * 4;   // float2 part[4][NB]

__device__ __forceinline__ float4 fma4(float x, float4 w, float4 a) {
    a.x = fmaf(x, w.x, a.x); a.y = fmaf(x, w.y, a.y);
    a.z = fmaf(x, w.z, a.z); a.w = fmaf(x, w.w, a.w);
    return a;
}

__global__ __launch_bounds__(512, 4) void fused_layer1_kernel(
    const float* __restrict__ X,
    const int*   __restrict__ aids,
    const float* __restrict__ W1,
    const float* __restrict__ b1,
    const float* __restrict__ W2,
    float*       __restrict__ part)   // float2 [4][NB]
{
    __shared__ __align__(16) float smem[S * DP];   // aids+hist, then xs, then red
    __shared__ int sidx[S];

    const int t = threadIdx.x;
    const int w = t >> 6, l = t & 63;
    const int c = blockIdx.x, hs = blockIdx.y;

    int* ai   = reinterpret_cast<int*>(smem);   // [NB] aspect ids
    int* hist = ai + NB;                        // [8][NA]
    int* cntf = hist + 8 * NA;                  // [NA]

    ai[t]       = aids[t];
    ai[t + 512] = aids[t + 512];
    __syncthreads();

    // per-wave histogram over its 128 ids via 64-bit ballots (deterministic)
    {
        const int id0 = ai[w * 128 + l];
        const int id1 = ai[w * 128 + 64 + l];
        #pragma unroll
        for (int a = 0; a < NA; ++a) {
            const unsigned long long m0 = __ballot(id0 == a);
            const unsigned long long m1 = __ballot(id1 == a);
            if (l == 0) hist[w * NA + a] = __popcll(m0) + __popcll(m1);
        }
    }
    __syncthreads();
    if (t < NA) {
        int sum = 0;
        #pragma unroll
        for (int ww = 0; ww < 8; ++ww) sum += hist[ww * NA + t];
        cntf[t] = sum;
    }
    __syncthreads();

    // map block -> (aspect aid, chunk jj); cv = valid samples in chunk
    int aid = 0, jj = 0, cv = 0;
    {
        int cb = 0, hit = 0;
        #pragma unroll
        for (int a = 0; a < NA; ++a) {
            const int n  = cntf[a];
            const int ca = (n + S - 1) / S;
            if (!hit && c < cb + ca) {
                aid = a; jj = c - cb; cv = min(S, n - jj * S); hit = 1;
            }
            cb += ca;
        }
        if (!hit) return;                       // c >= total chunks
    }

    // wave 0: stable extraction of occurrences jj*16 .. jj*16+cv-1 of aid
    if (w == 0) {
        const int j0 = jj * S;
        int running = 0;
        for (int base = 0; base < NB; base += 64) {
            const int id = ai[base + l];
            const unsigned long long m = __ballot(id == aid);
            const int pre = running + __popcll(m & ((1ull << l) - 1));
            if (id == aid) {
                const int r = pre - j0;
                if (r >= 0 && r < S) sidx[r] = base + l;
            }
            running += __popcll(m);
        }
    }
    __syncthreads();

    // stage 16 X rows (192 float4 each), coalesced; overwrites ai/hist/cntf
    for (int i = t; i < S * (D / 4); i += 512) {
        const int r = i / (D / 4), c4 = i - r * (D / 4);
        *reinterpret_cast<float4*>(&smem[r * DP + c4 * 4]) =
            reinterpret_cast<const float4*>(X + (size_t)sidx[min(r, cv - 1)] * D)[c4];
    }
    __syncthreads();

    const int sq = l >> 4;                      // sample quad 0..3
    const int cq = l & 15;                      // col quad within 64-col slice
    const int d0 = w * (D / 8);                 // 96 rows per wave
    const float* xb = &smem[(sq * 4) * DP + d0];
    const float4* W1p = reinterpret_cast<const float4*>(W1 + (size_t)aid * (D * H))
                        + (size_t)d0 * (H / 4) + hs * 16 + cq;

    float4 a0 = {0,0,0,0}, a1 = {0,0,0,0}, a2 = {0,0,0,0}, a3 = {0,0,0,0};
    #pragma unroll 3
    for (int d4 = 0; d4 < D / 8; d4 += 4) {
        const float4 x0 = *reinterpret_cast<const float4*>(xb + d4);
        const float4 x1 = *reinterpret_cast<const float4*>(xb + DP + d4);
        const float4 x2 = *reinterpret_cast<const float4*>(xb + 2 * DP + d4);
        const float4 x3 = *reinterpret_cast<const float4*>(xb + 3 * DP + d4);
        float4 wv;
        wv = W1p[(size_t)(d4 + 0) * (H / 4)];
        a0 = fma4(x0.x, wv, a0); a1 = fma4(x1.x, wv, a1);
        a2 = fma4(x2.x, wv, a2); a3 = fma4(x3.x, wv, a3);
        wv = W1p[(size_t)(d4 + 1) * (H / 4)];
        a0 = fma4(x0.y, wv, a0); a1 = fma4(x1.y, wv, a1);
        a2 = fma4(x2.y, wv, a2); a3 = fma4(x3.y, wv, a3);
        wv = W1p[(size_t)(d4 + 2) * (H / 4)];
        a0 = fma4(x0.z, wv, a0); a1 = fma4(x1.z, wv, a1);
        a2 = fma4(x2.z, wv, a2); a3 = fma4(x3.z, wv, a3);
        wv = W1p[(size_t)(d4 + 3) * (H / 4)];
        a0 = fma4(x0.w, wv, a0); a1 = fma4(x1.w, wv, a1);
        a2 = fma4(x2.w, wv, a2); a3 = fma4(x3.w, wv, a3);
    }
    __syncthreads();                            // done reading xs

    // overlay reduce buffer: red[w][s][cq] float4 = 32 KB
    float4* red = reinterpret_cast<float4*>(smem);
    red[(w * S + sq * 4 + 0) * 16 + cq] = a0;
    red[(w * S + sq * 4 + 1) * 16 + cq] = a1;
    red[(w * S + sq * 4 + 2) * 16 + cq] = a2;
    red[(w * S + sq * 4 + 3) * 16 + cq] = a3;
    __syncthreads();

    if (t < 256) {
        const int s = t >> 4, q = t & 15;
        float4 v = red[s * 16 + q];
        #pragma unroll
        for (int ww = 1; ww < 8; ++ww) {
            const float4 r = red[(ww * S + s) * 16 + q];
            v.x += r.x; v.y += r.y; v.z += r.z; v.w += r.w;
        }
        const float4 bv = reinterpret_cast<const float4*>(
            b1 + (size_t)aid * H + hs * 64)[q];
        float4 o;
        o.x = fmaxf(v.x + bv.x, 0.f);
        o.y = fmaxf(v.y + bv.y, 0.f);
        o.z = fmaxf(v.z + bv.z, 0.f);
        o.w = fmaxf(v.w + bv.w, 0.f);

        const float4* W2v = reinterpret_cast<const float4*>(
            W2 + (size_t)aid * (H * 2) + hs * 128 + q * 8);
        const float4 w2a = W2v[0];
        const float4 w2b = W2v[1];
        float p0 = o.x * w2a.x + o.y * w2a.z + o.z * w2b.x + o.w * w2b.z;
        float p1 = o.x * w2a.y + o.y * w2a.w + o.z * w2b.y + o.w * w2b.w;
        #pragma unroll
        for (int m = 1; m < 16; m <<= 1) {
            p0 += __shfl_xor(p0, m, 64);
            p1 += __shfl_xor(p1, m, 64);
        }
        if (q == 0) {
            reinterpret_cast<float2*>(part)[hs * NB + sidx[min(s, cv - 1)]] =
                make_float2(p0, p1);   // padded slots rewrite same value: benign
        }
    }
}

__global__ void finish_kernel(const int* __restrict__ aids,
                              const float* __restrict__ part,
                              const float* __restrict__ b2,
                              float* __restrict__ out)
{
    const int i = blockIdx.x * 512 + threadIdx.x;
    if (i >= NB * 2) return;
    const int s = i >> 1, o = i & 1;
    float v = b2[aids[s] * 2 + o];
    #pragma unroll
    for (int hs = 0; hs < 4; ++hs)
        v += part[(hs * NB + s) * 2 + o];
    out[i] = v;
}

// ---------------- fallback (round-1 monolithic kernel) ----------------
__global__ __launch_bounds__(256, 4) void aspect_mlp_fallback(
    const float* __restrict__ X, const int* __restrict__ aspect_ids,
    const float* __restrict__ W1_embs, const float* __restrict__ b1_embs,
    const float* __restrict__ W2_embs, const float* __restrict__ b2_embs,
    float* __restrict__ out)
{
    __shared__ float xs[D];
    __shared__ float pl[4][H];
    __shared__ float red[4][2];
    const int b = blockIdx.x, t = threadIdx.x, w = t >> 6, l = t & 63;
    const int aid = aspect_ids[b];
    const float4* Xr = reinterpret_cast<const float4*>(X + (size_t)b * D);
    if (t < D / 4) reinterpret_cast<float4*>(xs)[t] = Xr[t];
    __syncthreads();
    const float4* W1v = reinterpret_cast<const float4*>(W1_embs + (size_t)aid * (D * H));
    float4 acc = make_float4(0.f, 0.f, 0.f, 0.f);
    const int d0 = w * (D / 4);
    for (int d = d0; d < d0 + D / 4; ++d) {
        const float xv = xs[d];
        const float4 wv = W1v[d * (H / 4) + l];
        acc.x = fmaf(xv, wv.x, acc.x); acc.y = fmaf(xv, wv.y, acc.y);
        acc.z = fmaf(xv, wv.z, acc.z); acc.w = fmaf(xv, wv.w, acc.w);
    }
    reinterpret_cast<float4*>(pl[w])[l] = acc;
    __syncthreads();
    const float o = fmaxf(pl[0][t] + pl[1][t] + pl[2][t] + pl[3][t] + b1_embs[aid * H + t], 0.f);
    const float2 w2 = reinterpret_cast<const float2*>(W2_embs)[aid * H + t];
    float p0 = o * w2.x, p1 = o * w2.y;
    for (int s = 32; s; s >>= 1) { p0 += __shfl_xor(p0, s, 64); p1 += __shfl_xor(p1, s, 64); }
    if (l == 0) { red[w][0] = p0; red[w][1] = p1; }
    __syncthreads();
    if (t == 0) {
        const float2 bias2 = reinterpret_cast<const float2*>(b2_embs)[aid];
        out[b * 2 + 0] = red[0][0] + red[1][0] + red[2][0] + red[3][0] + bias2.x;
        out[b * 2 + 1] = red[0][1] + red[1][1] + red[2][1] + red[3][1] + bias2.y;
    }
}

extern "C" void kernel_launch(void* const* d_in, const int* in_sizes, int n_in,
                              void* d_out, int out_size, void* d_ws, size_t ws_size,
                              hipStream_t stream) {
    const float* X          = (const float*)d_in[0];
    const int*   aspect_ids = (const int*)d_in[1];
    const float* W1_embs    = (const float*)d_in[2];
    const float* b1_embs    = (const float*)d_in[3];
    const float* W2_embs    = (const float*)d_in[4];
    const float* b2_embs    = (const float*)d_in[5];
    float*       out        = (float*)d_out;

    const int Brt = in_sizes[0] / D;
    const int na  = in_sizes[2] / (D * H);

    if (Brt != NB || na != NA || ws_size < WS_NEEDED) {
        aspect_mlp_fallback<<<Brt, 256, 0, stream>>>(
            X, aspect_ids, W1_embs, b1_embs, W2_embs, b2_embs, out);
        return;
    }

    float* part = (float*)d_ws;

    fused_layer1_kernel<<<dim3(CH_CAP, 4), 512, 0, stream>>>(
        X, aspect_ids, W1_embs, b1_embs, W2_embs, part);
    finish_kernel<<<4, 512, 0, stream>>>(aspect_ids, part, b2_embs, out);
}